// Round 3
// baseline (68.258 us; speedup 1.0000x reference)
//
#include <hip/hip_runtime.h>
#include <math.h>

#define NN 256
#define DD 256
#define KK 16
#define M_MARGIN 0.6f
#define T_THRESH 0.0025f
#define EPS 1e-12f

// Completion-flag sentinels. Two DISTINCT words: the harness's ws poison is a
// single-constant fill, so a stale/poisoned flag pair (c,c) can never match
// (SA,SB). All protocol traffic uses device-scope atomics (coherent across
// XCDs; RMW reads pull from the coherence point, immune to stale per-XCD L2).
#define SENT_A 0x13579BDFu
#define SENT_B 0x2468ACE1u

// Single fused dispatch. Block i handles row i with 1024 threads: 4 lanes
// (s = t&3) share candidate j = t>>2, splitting the D-loop four ways;
// partials combine via 2 __shfl_xor steps. Pass 1 computes q = y_j.y_i,
// nn = y_j.y_j, uu = y_i.y_i; after ranking, only the <=16 neighbor groups
// run pass 2 (qt, vv, cross) under exec-mask. Gram identity
// ||a_i - a_j||^2 = 2 - 2*(y_i.y_j)/(n_i*n_j). Blocks i>0 publish partials
// via atomicExch + fence + 2 sentinel flags; block 0's wave 0 polls, reduces,
// and stores the scalar — no second kernel, no memset, no atomic contention.
__global__ void __launch_bounds__(1024) blcd_fused_kernel(
    const float* __restrict__ yi, const float* __restrict__ yit,
    float* __restrict__ out, float* __restrict__ ws)
{
    __shared__ float s_yi[DD];    // raw row i
    __shared__ float s_yit[DD];   // raw row i (tilde) — read only by pass 2
    __shared__ float sdis[NN];    // dis_yii[i][:]
    __shared__ float red[16];     // wave partials for final reduce

    float* __restrict__ partial = ws;                       // [NN] floats
    unsigned* __restrict__ fa = (unsigned*)(ws + NN);       // [NN] flags A
    unsigned* __restrict__ fb = (unsigned*)(ws + 2 * NN);   // [NN] flags B

    const int i = blockIdx.x;
    const int t = threadIdx.x;    // 0..1023
    const int j = t >> 2;         // candidate row 0..255
    const int s = t & 3;          // quarter of the D-range
    const int w = t >> 6;         // wave id 0..15

    // Stage row i (+tilde). Norms fold into pass 1 / pass 2.
    if (t < DD) {
        s_yi[t]  = yi [i * DD + t];
        s_yit[t] = yit[i * DD + t];
    }

    // Prefetch this lane's quarter of row j: d4 = 4k + s. Lanes 4g..4g+3 read
    // 4 adjacent float4 (64B contiguous) — fully coalesced.
    const float4* __restrict__ rj = (const float4*)(yi + j * DD);
    float4 p[16];
    #pragma unroll
    for (int k = 0; k < 16; ++k) p[k] = rj[4 * k + s];

    __syncthreads();

    // Pass 1: q = y_j.u, nn = y_j.y_j, uu = u.u  (u = row i from LDS).
    const float4* __restrict__ si = (const float4*)s_yi;
    float4 q4  = make_float4(0.f, 0.f, 0.f, 0.f);
    float4 nn4 = make_float4(0.f, 0.f, 0.f, 0.f);
    float4 uu4 = make_float4(0.f, 0.f, 0.f, 0.f);
    #pragma unroll
    for (int k = 0; k < 16; ++k) {
        const float4 y = p[k];
        const float4 u = si[4 * k + s];
        q4.x  += y.x * u.x; q4.y  += y.y * u.y; q4.z  += y.z * u.z; q4.w  += y.w * u.w;
        nn4.x += y.x * y.x; nn4.y += y.y * y.y; nn4.z += y.z * y.z; nn4.w += y.w * y.w;
        uu4.x += u.x * u.x; uu4.y += u.y * u.y; uu4.z += u.z * u.z; uu4.w += u.w * u.w;
    }
    float q  = (q4.x  + q4.y ) + (q4.z  + q4.w );
    float nn = (nn4.x + nn4.y) + (nn4.z + nn4.w);
    float uu = (uu4.x + uu4.y) + (uu4.z + uu4.w);
    q  += __shfl_xor(q,  1, 64);  q  += __shfl_xor(q,  2, 64);
    nn += __shfl_xor(nn, 1, 64);  nn += __shfl_xor(nn, 2, 64);
    uu += __shfl_xor(uu, 1, 64);  uu += __shfl_xor(uu, 2, 64);

    const float inv_ni = 1.0f / sqrtf(uu + EPS);
    const float inv_nt = 1.0f / sqrtf(nn + EPS);
    const float c   = q * inv_nt * inv_ni;
    const float myv = 0.5f * sqrtf(fmaxf(2.0f - 2.0f * c, 0.0f) + EPS);
    if (s == 0) sdis[j] = myv;
    __syncthreads();

    // Stable rank == top_k position (ties -> lower index first), 4-way split.
    int rank = 0;
    const float4* sd4 = (const float4*)sdis;
    #pragma unroll
    for (int m = 0; m < 16; ++m) {
        const int k = 4 * m + s;
        float4 v = sd4[k];
        const int jj = k * 4;
        rank += (v.x < myv || (v.x == myv && (jj + 0) < j)) ? 1 : 0;
        rank += (v.y < myv || (v.y == myv && (jj + 1) < j)) ? 1 : 0;
        rank += (v.z < myv || (v.z == myv && (jj + 2) < j)) ? 1 : 0;
        rank += (v.w < myv || (v.w == myv && (jj + 3) < j)) ? 1 : 0;
    }
    rank += __shfl_xor(rank, 1, 64);
    rank += __shfl_xor(rank, 2, 64);

    // Pass 2: only neighbor groups (rank 1..16) touch the tilde row.
    float contrib = 0.0f;
    if (rank >= 1 && rank <= KK) {
        const float4* __restrict__ sit = (const float4*)s_yit;
        float4 qt4 = make_float4(0.f, 0.f, 0.f, 0.f);
        float4 vv4 = make_float4(0.f, 0.f, 0.f, 0.f);
        float4 uv4 = make_float4(0.f, 0.f, 0.f, 0.f);
        #pragma unroll
        for (int k = 0; k < 16; ++k) {
            const float4 y = p[k];
            const float4 u = si [4 * k + s];
            const float4 v = sit[4 * k + s];
            qt4.x += y.x * v.x; qt4.y += y.y * v.y; qt4.z += y.z * v.z; qt4.w += y.w * v.w;
            vv4.x += v.x * v.x; vv4.y += v.y * v.y; vv4.z += v.z * v.z; vv4.w += v.w * v.w;
            uv4.x += u.x * v.x; uv4.y += u.y * v.y; uv4.z += u.z * v.z; uv4.w += u.w * v.w;
        }
        float qt = (qt4.x + qt4.y) + (qt4.z + qt4.w);
        float vv = (vv4.x + vv4.y) + (vv4.z + vv4.w);
        float uv = (uv4.x + uv4.y) + (uv4.z + uv4.w);
        qt += __shfl_xor(qt, 1, 64);  qt += __shfl_xor(qt, 2, 64);
        vv += __shfl_xor(vv, 1, 64);  vv += __shfl_xor(vv, 2, 64);
        uv += __shfl_xor(uv, 1, 64);  uv += __shfl_xor(uv, 2, 64);

        const float inv_nit = 1.0f / sqrtf(vv + EPS);
        const float ct   = qt * inv_nt * inv_nit;
        const float myvt = 0.5f * sqrtf(fmaxf(2.0f - 2.0f * ct, 0.0f) + EPS);
        if (s == 0) {
            const float dd = myv - myvt;
            contrib = dd * dd - T_THRESH;            // e1 term
            if (rank == 1) {                         // e2 hinge: j is 2nd-NN
                const float cc = uv * inv_ni * inv_nit;
                const float d_iit = 0.5f * sqrtf(fmaxf(2.0f - 2.0f * cc, 0.0f) + EPS);
                contrib += fmaxf(d_iit + M_MARGIN - myv, 0.0f);
            }
        }
    }

    // Block reduce (16 waves).
    #pragma unroll
    for (int off = 32; off > 0; off >>= 1) contrib += __shfl_down(contrib, off, 64);
    if ((t & 63) == 0) red[w] = contrib;
    __syncthreads();

    if (i != 0) {
        if (t == 0) {
            float tot = ((red[0]  + red[1])  + (red[2]  + red[3]))
                      + ((red[4]  + red[5])  + (red[6]  + red[7]))
                      + ((red[8]  + red[9])  + (red[10] + red[11]))
                      + ((red[12] + red[13]) + (red[14] + red[15]));
            atomicExch(&partial[i], tot);            // device-scope publish
            __threadfence();                         // partial before flags
            atomicExch(&fa[i], SENT_A);
            atomicExch(&fb[i], SENT_B);
        }
        return;
    }

    // Block 0, wave 0: poll the 255 flag pairs (4 slots per lane), then
    // coherently read partials (atomicAdd +0.0f), reduce, add own, store.
    if (t < 64) {
        float tot = ((red[0]  + red[1])  + (red[2]  + red[3]))
                  + ((red[4]  + red[5])  + (red[6]  + red[7]))
                  + ((red[8]  + red[9])  + (red[10] + red[11]))
                  + ((red[12] + red[13]) + (red[14] + red[15]));
        const int base = 4 * t;                      // slots base..base+3
        bool d0 = (base == 0);                       // i=0 is ourselves
        bool d1 = false, d2 = false, d3 = false;
        while (true) {
            if (!d0) d0 = (atomicAdd(&fa[base + 0], 0u) == SENT_A) &&
                          (atomicAdd(&fb[base + 0], 0u) == SENT_B);
            if (!d1) d1 = (atomicAdd(&fa[base + 1], 0u) == SENT_A) &&
                          (atomicAdd(&fb[base + 1], 0u) == SENT_B);
            if (!d2) d2 = (atomicAdd(&fa[base + 2], 0u) == SENT_A) &&
                          (atomicAdd(&fb[base + 2], 0u) == SENT_B);
            if (!d3) d3 = (atomicAdd(&fa[base + 3], 0u) == SENT_A) &&
                          (atomicAdd(&fb[base + 3], 0u) == SENT_B);
            if (__all(d0 && d1 && d2 && d3)) break;
            __builtin_amdgcn_s_sleep(1);
        }
        float acc = 0.0f;
        if (base != 0) acc += atomicAdd(&partial[base + 0], 0.0f);
        acc += atomicAdd(&partial[base + 1], 0.0f);
        acc += atomicAdd(&partial[base + 2], 0.0f);
        acc += atomicAdd(&partial[base + 3], 0.0f);
        #pragma unroll
        for (int off = 32; off > 0; off >>= 1) acc += __shfl_down(acc, off, 64);
        if (t == 0) out[0] = acc + tot;
    }
}

extern "C" void kernel_launch(void* const* d_in, const int* in_sizes, int n_in,
                              void* d_out, int out_size, void* d_ws, size_t ws_size,
                              hipStream_t stream) {
    (void)in_sizes; (void)n_in; (void)out_size; (void)ws_size;

    const float* yi  = (const float*)d_in[0];
    const float* yit = (const float*)d_in[1];
    float* out = (float*)d_out;
    float* ws  = (float*)d_ws;

    blcd_fused_kernel<<<NN, 1024, 0, stream>>>(yi, yit, out, ws);
}

// Round 4
// 62.724 us; speedup vs baseline: 1.0882x; 1.0882x over previous
//
#include <hip/hip_runtime.h>
#include <math.h>

#define NN 256
#define DD 256
#define KK 16
#define M_MARGIN 0.6f
#define T_THRESH 0.0025f
#define EPS 1e-12f

// Two dispatches (best measured structure, R1/R2). Block i handles row i with
// 1024 threads: 4 lanes (s = t&3) share candidate j = t>>2. Pass 1 computes
// only q = y_j.y_i and nn = y_j.y_j; ranking uses the monotone key
// key = q / sqrt(nn+eps)  (dis is monotone-DECREASING in key; the common
// positive factor 1/|y_i| cannot change the order). After ranking, the 16
// neighbor groups (rank 1..16) publish (j, q, nn) into LDS slot rank-1; all
// waves but wave 0 exit, and wave 0 (4 lanes x 16 neighbors = 64 lanes) does
// the tilde-row pass with L2-hot global reads, computes e1 + e2, reduces and
// stores partial[i]. Gram identity ||a_i-a_j||^2 = 2 - 2*(y_i.y_j)/(n_i n_j).
__global__ void __launch_bounds__(1024) blcd_row_kernel(
    const float* __restrict__ yi, const float* __restrict__ yit,
    float* __restrict__ partial)
{
    __shared__ float s_yi[DD];     // raw row i
    __shared__ float s_yit[DD];    // raw row i (tilde) — read only by wave 0
    __shared__ float skey[NN];     // ranking keys
    __shared__ int   nbrj [KK];    // neighbor row index, slot = rank-1
    __shared__ float nbrq [KK];    // neighbor q  = y_j.y_i
    __shared__ float nbrnn[KK];    // neighbor nn = y_j.y_j

    const int i = blockIdx.x;
    const int t = threadIdx.x;    // 0..1023
    const int j = t >> 2;         // candidate row 0..255
    const int s = t & 3;          // quarter of the D-range

    // Issue staging loads, THEN prefetch, THEN LDS stores: the ds_write only
    // waits for a/b (vmcnt(16)), so the 16 prefetch loads stay in flight
    // across the store + barrier (this overlap was the R1 win; R2 lost it).
    float a = 0.0f, b = 0.0f;
    if (t < DD) {
        a = yi [i * DD + t];
        b = yit[i * DD + t];
    }

    // Prefetch this lane's quarter of row j: d4 = 4k + s. Lanes 4g..4g+3 read
    // 4 adjacent float4 (64B contiguous) — fully coalesced.
    const float4* __restrict__ rj = (const float4*)(yi + j * DD);
    float4 p[16];
    #pragma unroll
    for (int k = 0; k < 16; ++k) p[k] = rj[4 * k + s];

    if (t < DD) { s_yi[t] = a; s_yit[t] = b; }
    __syncthreads();

    // Pass 1: q = y_j.u, nn = y_j.y_j  (u = row i from LDS broadcast).
    const float4* __restrict__ si = (const float4*)s_yi;
    float4 q4  = make_float4(0.f, 0.f, 0.f, 0.f);
    float4 nn4 = make_float4(0.f, 0.f, 0.f, 0.f);
    #pragma unroll
    for (int k = 0; k < 16; ++k) {
        const float4 y = p[k];
        const float4 u = si[4 * k + s];
        q4.x  += y.x * u.x; q4.y  += y.y * u.y; q4.z  += y.z * u.z; q4.w  += y.w * u.w;
        nn4.x += y.x * y.x; nn4.y += y.y * y.y; nn4.z += y.z * y.z; nn4.w += y.w * y.w;
    }
    float q  = (q4.x  + q4.y ) + (q4.z  + q4.w );
    float nn = (nn4.x + nn4.y) + (nn4.z + nn4.w);
    q  += __shfl_xor(q,  1, 64);  q  += __shfl_xor(q,  2, 64);
    nn += __shfl_xor(nn, 1, 64);  nn += __shfl_xor(nn, 2, 64);

    const float key = q * (1.0f / sqrtf(nn + EPS));   // descending ~ dis ascending
    if (s == 0) skey[j] = key;
    __syncthreads();

    // Stable rank: position in ascending-dis order == #{key_j' > key_j} +
    // #{key_j' == key_j && j' < j}. 4-way split; reads are 4-address
    // broadcasts (conflict-free).
    int rank = 0;
    const float4* sk4 = (const float4*)skey;
    #pragma unroll
    for (int m = 0; m < 16; ++m) {
        const int k = 4 * m + s;
        float4 v = sk4[k];
        const int jj = k * 4;
        rank += (v.x > key || (v.x == key && (jj + 0) < j)) ? 1 : 0;
        rank += (v.y > key || (v.y == key && (jj + 1) < j)) ? 1 : 0;
        rank += (v.z > key || (v.z == key && (jj + 2) < j)) ? 1 : 0;
        rank += (v.w > key || (v.w == key && (jj + 3) < j)) ? 1 : 0;
    }
    rank += __shfl_xor(rank, 1, 64);
    rank += __shfl_xor(rank, 2, 64);

    // Publish the 16 neighbors (ranks are a permutation -> slots fill exactly).
    if (s == 0 && rank >= 1 && rank <= KK) {
        nbrj [rank - 1] = j;
        nbrq [rank - 1] = q;
        nbrnn[rank - 1] = nn;
    }
    __syncthreads();

    if (t >= 64) return;          // waves 1..15 done; LDS stays valid

    // Wave 0: 4 lanes per neighbor g (slot g == rank g+1). Neighbor rows are
    // L2-hot (every block just read them).
    const int g  = t >> 2;
    const int s2 = t & 3;
    const int   jn  = nbrj [g];
    const float qn  = nbrq [g];
    const float nnn = nbrnn[g];

    const float4* __restrict__ rn  = (const float4*)(yi + jn * DD);
    const float4* __restrict__ sit = (const float4*)s_yit;
    float4 qt4 = make_float4(0.f, 0.f, 0.f, 0.f);
    float4 vv4 = make_float4(0.f, 0.f, 0.f, 0.f);
    float4 uv4 = make_float4(0.f, 0.f, 0.f, 0.f);
    float4 uu4 = make_float4(0.f, 0.f, 0.f, 0.f);
    #pragma unroll
    for (int k = 0; k < 16; ++k) {
        const float4 y = rn [4 * k + s2];
        const float4 u = si [4 * k + s2];
        const float4 v = sit[4 * k + s2];
        qt4.x += y.x * v.x; qt4.y += y.y * v.y; qt4.z += y.z * v.z; qt4.w += y.w * v.w;
        vv4.x += v.x * v.x; vv4.y += v.y * v.y; vv4.z += v.z * v.z; vv4.w += v.w * v.w;
        uv4.x += u.x * v.x; uv4.y += u.y * v.y; uv4.z += u.z * v.z; uv4.w += u.w * v.w;
        uu4.x += u.x * u.x; uu4.y += u.y * u.y; uu4.z += u.z * u.z; uu4.w += u.w * u.w;
    }
    float qt = (qt4.x + qt4.y) + (qt4.z + qt4.w);
    float vv = (vv4.x + vv4.y) + (vv4.z + vv4.w);
    float uv = (uv4.x + uv4.y) + (uv4.z + uv4.w);
    float uu = (uu4.x + uu4.y) + (uu4.z + uu4.w);
    qt += __shfl_xor(qt, 1, 64);  qt += __shfl_xor(qt, 2, 64);
    vv += __shfl_xor(vv, 1, 64);  vv += __shfl_xor(vv, 2, 64);
    uv += __shfl_xor(uv, 1, 64);  uv += __shfl_xor(uv, 2, 64);
    uu += __shfl_xor(uu, 1, 64);  uu += __shfl_xor(uu, 2, 64);

    const float inv_ni  = 1.0f / sqrtf(uu  + EPS);
    const float inv_nit = 1.0f / sqrtf(vv  + EPS);
    const float inv_nt  = 1.0f / sqrtf(nnn + EPS);
    const float c    = qn * inv_nt * inv_ni;
    const float ct   = qt * inv_nt * inv_nit;
    const float myv  = 0.5f * sqrtf(fmaxf(2.0f - 2.0f * c , 0.0f) + EPS);
    const float myvt = 0.5f * sqrtf(fmaxf(2.0f - 2.0f * ct, 0.0f) + EPS);

    float contrib = 0.0f;
    if (s2 == 0) {
        const float dd = myv - myvt;
        contrib = dd * dd - T_THRESH;                // e1 term (all 16 nbrs)
        if (g == 0) {                                // slot 0 == rank 1 == 2nd-NN
            const float cc = uv * inv_ni * inv_nit;
            const float d_iit = 0.5f * sqrtf(fmaxf(2.0f - 2.0f * cc, 0.0f) + EPS);
            contrib += fmaxf(d_iit + M_MARGIN - myv, 0.0f);
        }
    }
    #pragma unroll
    for (int off = 32; off > 0; off >>= 1) contrib += __shfl_down(contrib, off, 64);
    if (t == 0) partial[i] = contrib;
}

// 256 partials -> scalar. One wave, shuffle-only, no LDS, no barrier.
__global__ void __launch_bounds__(64) blcd_reduce_kernel(
    const float* __restrict__ partial, float* __restrict__ out)
{
    const int t = threadIdx.x;
    const float4 v4 = ((const float4*)partial)[t];   // 64 lanes x 4 = 256
    float v = (v4.x + v4.y) + (v4.z + v4.w);
    #pragma unroll
    for (int off = 32; off > 0; off >>= 1) v += __shfl_down(v, off, 64);
    if (t == 0) out[0] = v;
}

extern "C" void kernel_launch(void* const* d_in, const int* in_sizes, int n_in,
                              void* d_out, int out_size, void* d_ws, size_t ws_size,
                              hipStream_t stream) {
    (void)in_sizes; (void)n_in; (void)out_size; (void)ws_size;

    const float* yi  = (const float*)d_in[0];
    const float* yit = (const float*)d_in[1];
    float* out = (float*)d_out;
    float* ws  = (float*)d_ws;

    blcd_row_kernel<<<NN, 1024, 0, stream>>>(yi, yit, ws);
    blcd_reduce_kernel<<<1, 64, 0, stream>>>(ws, out);
}